// Round 3
// baseline (232.894 us; speedup 1.0000x reference)
//
#include <hip/hip_runtime.h>

// Sparsemax over last dim, rows of N=512 fp32.
//
// Structure: PERSISTENT waves, software-pipelined over row-batches.
// Previous rounds established (rocprof): VALU work cut 2.4x -> no time change;
// 4-row per-wave ILP -> no time change. Both pipes idle ~65% simultaneously.
// Diagnosis: burst-load -> solve -> burst-store structure drains the memory
// pipe during every solve. Fix: each wave handles ~8 batches of RPW=2 rows,
// issuing batch b+1's global loads BEFORE solving batch b, so HBM latency
// hides under the ~8-iteration Michelot solve and the memory system never
// drains. 1024 blocks x 4 waves = 16 waves/CU, each with 4KB continuously in
// flight.
//
// Numerics: identical per-row 64-lane layout, DPP max/sum trees, warm start
// (tau = z_max - 1), update order and break condition as the passing rounds
// -> bitwise-identical tau -> absmax 0.0.

#define ROW_N 512
#define LANES 64
#define EPL 8  // elements per lane per row
#define RPW 2  // rows per batch per wave
#define WPB 4  // waves per block
#define NBLOCKS 1024

// One DPP step: v = v + dpp_move(v). bound_ctrl=1 -> out-of-bounds lanes read 0
// (additive identity).
#define DPP_ADD_STEP(v, ctrl, rmask)                                        \
  v += __int_as_float(__builtin_amdgcn_update_dpp(                          \
      0, __float_as_int(v), ctrl, rmask, 0xf, true))

// Full-wave (64-lane) sum; returns the total, uniform across the wave.
__device__ inline float wave_sum64(float v) {
  DPP_ADD_STEP(v, 0x111, 0xf);  // row_shr:1
  DPP_ADD_STEP(v, 0x112, 0xf);  // row_shr:2
  DPP_ADD_STEP(v, 0x114, 0xf);  // row_shr:4
  DPP_ADD_STEP(v, 0x118, 0xf);  // row_shr:8  -> lane15 of each row = row sum
  DPP_ADD_STEP(v, 0x142, 0xa);  // row_bcast:15 -> lanes 31, 63 accumulate
  DPP_ADD_STEP(v, 0x143, 0xc);  // row_bcast:31 -> lane 63 = wave total
  return __int_as_float(__builtin_amdgcn_readlane(__float_as_int(v), 63));
}

// Full-wave max: identity-old variant (invalid/masked lanes contribute v).
#define DPP_MAX_STEP(v, ctrl, rmask)                                        \
  v = fmaxf(v, __int_as_float(__builtin_amdgcn_update_dpp(                  \
             __float_as_int(v), __float_as_int(v), ctrl, rmask, 0xf, false)))

__device__ inline float wave_max64(float v) {
  DPP_MAX_STEP(v, 0x111, 0xf);
  DPP_MAX_STEP(v, 0x112, 0xf);
  DPP_MAX_STEP(v, 0x114, 0xf);
  DPP_MAX_STEP(v, 0x118, 0xf);
  DPP_MAX_STEP(v, 0x142, 0xa);
  DPP_MAX_STEP(v, 0x143, 0xc);
  return __int_as_float(__builtin_amdgcn_readlane(__float_as_int(v), 63));
}

__global__ __launch_bounds__(WPB * 64) void sparsemax_kernel(
    const float* __restrict__ x, float* __restrict__ out, int nrows) {
  const int lane = threadIdx.x & 63;
  const int wave = threadIdx.x >> 6;
  const int wid = blockIdx.x * WPB + wave;
  const int nwaves = gridDim.x * WPB;
  const int npairs = (nrows + RPW - 1) / RPW;
  if (wid >= npairs) return;

#define LOAD_PAIR(pidx, buf)                                                \
  do {                                                                      \
    _Pragma("unroll") for (int r = 0; r < RPW; ++r) {                       \
      const int row_ = min((pidx) * RPW + r, nrows - 1);                    \
      const float4* xr_ = (const float4*)(x + (size_t)row_ * ROW_N);        \
      buf[r][0] = xr_[lane];                                                \
      buf[r][1] = xr_[lane + LANES];                                        \
    }                                                                       \
  } while (0)

  float4 cur[RPW][2];
  LOAD_PAIR(wid, cur);

  for (int p = wid; p < npairs; p += nwaves) {
    // ---- issue next batch's loads first (prefetch over this batch's solve)
    const int pn = p + nwaves;
    const bool hn = pn < npairs;
    float4 nxt[RPW][2];
    if (hn) LOAD_PAIR(pn, nxt);

    // ---- unpack current batch
    float z[RPW][EPL];
#pragma unroll
    for (int r = 0; r < RPW; ++r) {
      z[r][0] = cur[r][0].x; z[r][1] = cur[r][0].y;
      z[r][2] = cur[r][0].z; z[r][3] = cur[r][0].w;
      z[r][4] = cur[r][1].x; z[r][5] = cur[r][1].y;
      z[r][6] = cur[r][1].z; z[r][7] = cur[r][1].w;
    }

    // ---- row max (stability shift), independent DPP chains
    float m[RPW];
#pragma unroll
    for (int r = 0; r < RPW; ++r) {
      float mm = z[r][0];
#pragma unroll
      for (int i = 1; i < EPL; ++i) mm = fmaxf(mm, z[r][i]);
      m[r] = mm;
    }
#pragma unroll
    for (int r = 0; r < RPW; ++r) m[r] = wave_max64(m[r]);
#pragma unroll
    for (int r = 0; r < RPW; ++r)
#pragma unroll
      for (int i = 0; i < EPL; ++i) z[r][i] -= m[r];

    // ---- Michelot, warm start tau = z_max - 1 = -1 (provable lower bound).
    float tau[RPW];
    int pc[RPW];
#pragma unroll
    for (int r = 0; r < RPW; ++r) { tau[r] = -1.0f; pc[r] = -1; }
    for (int iter = 0; iter < 64; ++iter) {
      float ls[RPW];
      int cnt[RPW];
#pragma unroll
      for (int r = 0; r < RPW; ++r) {
        float s = 0.0f;
        int c = 0;
#pragma unroll
        for (int i = 0; i < EPL; ++i) {
          bool g = z[r][i] > tau[r];
          c += (int)__popcll(__ballot(g));  // SALU: s_bcnt1 + s_add
          s += g ? z[r][i] : 0.0f;          // VALU: cndmask + add
        }
        ls[r] = s;
        cnt[r] = c;
      }
#pragma unroll
      for (int r = 0; r < RPW; ++r) ls[r] = wave_sum64(ls[r]);
      bool allstable = true;
#pragma unroll
      for (int r = 0; r < RPW; ++r) {
        tau[r] = (ls[r] - 1.0f) / (float)cnt[r];
        allstable = allstable && (cnt[r] == pc[r]);
        pc[r] = cnt[r];
      }
      if (allstable) break;  // supports stable -> taus are fixed points
    }

    // ---- store this batch
#pragma unroll
    for (int r = 0; r < RPW; ++r) {
      if (p * RPW + r < nrows) {
        float4* outr = (float4*)(out + (size_t)(p * RPW + r) * ROW_N);
        float4 oa = {fmaxf(z[r][0] - tau[r], 0.0f),
                     fmaxf(z[r][1] - tau[r], 0.0f),
                     fmaxf(z[r][2] - tau[r], 0.0f),
                     fmaxf(z[r][3] - tau[r], 0.0f)};
        float4 ob = {fmaxf(z[r][4] - tau[r], 0.0f),
                     fmaxf(z[r][5] - tau[r], 0.0f),
                     fmaxf(z[r][6] - tau[r], 0.0f),
                     fmaxf(z[r][7] - tau[r], 0.0f)};
        outr[lane] = oa;
        outr[lane + LANES] = ob;
      }
    }

    // ---- rotate prefetch buffer (compiler places the vmcnt wait here)
    if (hn) {
#pragma unroll
      for (int r = 0; r < RPW; ++r) {
        cur[r][0] = nxt[r][0];
        cur[r][1] = nxt[r][1];
      }
    }
  }
#undef LOAD_PAIR
}

extern "C" void kernel_launch(void* const* d_in, const int* in_sizes, int n_in,
                              void* d_out, int out_size, void* d_ws,
                              size_t ws_size, hipStream_t stream) {
  const float* x = (const float*)d_in[0];
  float* out = (float*)d_out;
  const int nrows = in_sizes[0] / ROW_N;
  const int npairs = (nrows + RPW - 1) / RPW;
  const int maxblocks = (npairs + WPB - 1) / WPB;
  const int blocks = maxblocks < NBLOCKS ? maxblocks : NBLOCKS;
  sparsemax_kernel<<<blocks, WPB * 64, 0, stream>>>(x, out, nrows);
}